// Round 7
// baseline (191.264 us; speedup 1.0000x reference)
//
#include <hip/hip_runtime.h>

// Problem constants (fixed by reference)
#define NB 8
#define NN 2048
#define KK 64
#define VV 64
#define SCALE 0.18033688011112043f  // (1/sqrt(64)) * log2(e)

// ===== MEASUREMENT ROUND: K1 and K3 bodies repeat REP times (z=0 makes
// reps idempotent; runtime z defeats compiler hoisting). Divide their
// profiled durations by REP. =====
#define REP 3

typedef __bf16 bfrag  __attribute__((ext_vector_type(8)));
typedef __bf16 bf16x4 __attribute__((ext_vector_type(4)));
typedef float  f32x4  __attribute__((ext_vector_type(4)));

// LDS byte offset within a tile with 128B rows, XOR-swizzled (G4)
__device__ __forceinline__ int swz(int row, int colByte) {
  return row * 128 + (colByte ^ ((row & 7) << 4));
}

__device__ __forceinline__ bfrag lds_frag(const unsigned short* base, int row, int colByte) {
  return *reinterpret_cast<const bfrag*>(reinterpret_cast<const char*>(base) + swz(row, colByte));
}

// 8 consecutive global fp32 -> bf16 MFMA fragment (v_cvt_pk via plain casts)
__device__ __forceinline__ bfrag g_frag(const float* __restrict__ g) {
  const float4* p = reinterpret_cast<const float4*>(g);
  float4 x = p[0], y = p[1];
  bfrag r;
  r[0] = (__bf16)x.x; r[1] = (__bf16)x.y; r[2] = (__bf16)x.z; r[3] = (__bf16)x.w;
  r[4] = (__bf16)y.x; r[5] = (__bf16)y.y; r[6] = (__bf16)y.z; r[7] = (__bf16)y.w;
  return r;
}

// ---- staging: 16 consecutive fp32 -> 16 bf16 into one LDS row ----
struct KS { float4 f[4]; };
__device__ __forceinline__ void k_load(KS& s, const float* __restrict__ g) {
  const float4* p = reinterpret_cast<const float4*>(g);
  s.f[0] = p[0]; s.f[1] = p[1]; s.f[2] = p[2]; s.f[3] = p[3];
}
__device__ __forceinline__ void k_write(const KS& s, unsigned short* lds, int row, int colByte) {
  const float* f = reinterpret_cast<const float*>(&s.f[0]);
  bfrag a, b;
#pragma unroll
  for (int j = 0; j < 8; ++j) a[j] = (__bf16)f[j];
#pragma unroll
  for (int j = 0; j < 8; ++j) b[j] = (__bf16)f[8 + j];
  *reinterpret_cast<bfrag*>(reinterpret_cast<char*>(lds) + swz(row, colByte)) = a;
  *reinterpret_cast<bfrag*>(reinterpret_cast<char*>(lds) + swz(row, colByte + 16)) = b;
}

// ---- V staging: rows (il, il+1) x 8 v -> transposed Vt[v][i] ----
struct VS { float4 f[4]; };
__device__ __forceinline__ void v_load(VS& s, const float* __restrict__ g) {
  const float4* p = reinterpret_cast<const float4*>(g);
  s.f[0] = p[0]; s.f[1] = p[1];
  const float4* q = reinterpret_cast<const float4*>(g + VV);
  s.f[2] = q[0]; s.f[3] = q[1];
}
__device__ __forceinline__ void v_write(const VS& s, unsigned short* lds, int il, int v0) {
  const float* lo = reinterpret_cast<const float*>(&s.f[0]);
  const float* hi = reinterpret_cast<const float*>(&s.f[2]);
#pragma unroll
  for (int j = 0; j < 8; ++j) {
    __bf16 two[2] = { (__bf16)lo[j], (__bf16)hi[j] };
    *reinterpret_cast<unsigned*>(reinterpret_cast<char*>(lds) + swz(v0 + j, il * 2)) =
        *reinterpret_cast<unsigned*>(two);
  }
}

// =====================================================================
// K1: per (b, o-tile 64, i-chunk 512): partial D[64] + partial U[64][64]
// -> scratch. (REP'd for measurement.)
// =====================================================================
#define CHUNK 512
#define IT 64
#define K1STEPS (CHUNK / IT)   // 8
#define SCR_STRIDE 4160        // 64*64 U + 64 D floats per chunk

__global__ void __launch_bounds__(256) attn_pass1(
    const float* __restrict__ key, const float* __restrict__ query,
    const float* __restrict__ value, float* __restrict__ scratch, int z)
{
  __shared__ __align__(16) unsigned short Kt[IT * KK];
  __shared__ __align__(16) unsigned short Vt[VV * IT];
  __shared__ __align__(16) unsigned short Et[64 * IT];
  __shared__ float Red[4][64];

  const int tid  = threadIdx.x;
  const int lane = tid & 63;
  const int wv   = tid >> 6;
  const int l15  = lane & 15;
  const int l4   = lane >> 4;

  const int b    = blockIdx.x & 7;          // batch -> XCD
  const int rest = blockIdx.x >> 3;
  const int ot   = rest & 31;               // o-tile (64)
  const int ci   = rest >> 5;               // i-chunk (512)
  const int o0   = ot * 64;
  const int ib0  = ci * CHUNK;

  const int krow = tid >> 2;          // 0..63
  const int kel  = (tid & 3) * 16;
  const int kcb  = (tid & 3) * 32;
  const int vil  = (tid & 31) * 2;
  const int vv0  = (tid >> 5) * 8;

  for (int rep = 0; rep < REP; ++rep) {
    // z==0: identical addresses every rep; runtime z defeats hoisting
    const float* Kg = key   + (size_t)b * NN * KK + (size_t)(rep * z);
    const float* Qg = query + (size_t)b * NN * KK + (size_t)(rep * z);
    const float* Vg = value + (size_t)b * NN * VV + (size_t)(rep * z);
    float* scr = scratch + (size_t)((b * 32 + ot) * 4 + ci) * SCR_STRIDE + (size_t)(rep * z);

    // Q fragments (B-op: o = l15, k = l4*8+j), direct from global
    bfrag qb0[4], qb1[4];
#pragma unroll
    for (int s = 0; s < 4; ++s) {
      const float* qr = Qg + (size_t)(o0 + s * 16 + l15) * KK;
      qb0[s] = g_frag(qr + l4 * 8);
      qb1[s] = g_frag(qr + 32 + l4 * 8);
    }

    KS ks; VS vs;
    k_load(ks, Kg + (size_t)(ib0 + krow) * KK + kel);
    v_load(vs, Vg + (size_t)(ib0 + vil) * VV + vv0);
    k_write(ks, Kt, krow, kcb);
    v_write(vs, Vt, vil, vv0);
    __syncthreads();

    f32x4 uacc[4];
    float Dacc[4] = {0.f, 0.f, 0.f, 0.f};
#pragma unroll
    for (int s = 0; s < 4; ++s) { f32x4 zz = {0.f, 0.f, 0.f, 0.f}; uacc[s] = zz; }

    for (int t = 0; t < K1STEPS; ++t) {
      if (t + 1 < K1STEPS) {
        k_load(ks, Kg + (size_t)(ib0 + (t + 1) * IT + krow) * KK + kel);
        v_load(vs, Vg + (size_t)(ib0 + (t + 1) * IT + vil) * VV + vv0);
      }
      // QK: S = K_tile . Q^T ; e = exp ; accumulate D ; write Et[o][i]
      bfrag a0 = lds_frag(Kt, wv * 16 + l15, l4 * 16);
      bfrag a1 = lds_frag(Kt, wv * 16 + l15, 64 + l4 * 16);
#pragma unroll
      for (int s = 0; s < 4; ++s) {
        f32x4 zz = {0.f, 0.f, 0.f, 0.f};
        zz = __builtin_amdgcn_mfma_f32_16x16x32_bf16(a0, qb0[s], zz, 0, 0, 0);
        zz = __builtin_amdgcn_mfma_f32_16x16x32_bf16(a1, qb1[s], zz, 0, 0, 0);
        f32x4 e;
#pragma unroll
        for (int r = 0; r < 4; ++r) e[r] = exp2f(zz[r] * SCALE);
        Dacc[s] += e[0] + e[1] + e[2] + e[3];
        bf16x4 pk;
#pragma unroll
        for (int r = 0; r < 4; ++r) pk[r] = (__bf16)e[r];
        *reinterpret_cast<bf16x4*>(reinterpret_cast<char*>(Et) +
                                   swz(s * 16 + l15, wv * 32 + l4 * 8)) = pk;
      }
      __syncthreads();   // A: Et ready; Kt reads complete
      if (t + 1 < K1STEPS) k_write(ks, Kt, krow, kcb);   // restage K
      // PV: U += V^T . E
      bfrag va0 = lds_frag(Vt, wv * 16 + l15, l4 * 16);
      bfrag va1 = lds_frag(Vt, wv * 16 + l15, 64 + l4 * 16);
#pragma unroll
      for (int s = 0; s < 4; ++s) {
        bfrag e0 = lds_frag(Et, s * 16 + l15, l4 * 16);
        bfrag e1 = lds_frag(Et, s * 16 + l15, 64 + l4 * 16);
        uacc[s] = __builtin_amdgcn_mfma_f32_16x16x32_bf16(va0, e0, uacc[s], 0, 0, 0);
        uacc[s] = __builtin_amdgcn_mfma_f32_16x16x32_bf16(va1, e1, uacc[s], 0, 0, 0);
      }
      __syncthreads();   // B: Vt/Et reads complete; staged Kt visible
      if (t + 1 < K1STEPS) v_write(vs, Vt, vil, vv0);    // restage V
    }

    // partial U -> scratch (v-major [v][o])
#pragma unroll
    for (int s = 0; s < 4; ++s)
#pragma unroll
      for (int r = 0; r < 4; ++r)
        scr[(wv * 16 + l4 * 4 + r) * 64 + s * 16 + l15] = uacc[s][r];

    // partial D -> scratch
#pragma unroll
    for (int s = 0; s < 4; ++s) {
      float d = Dacc[s];
      d += __shfl_xor(d, 16, 64);
      d += __shfl_xor(d, 32, 64);
      if (lane < 16) Red[wv][s * 16 + lane] = d;
    }
    __syncthreads();
    if (tid < 64)
      scr[4096 + tid] = Red[0][tid] + Red[1][tid] + Red[2][tid] + Red[3][tid];
    __syncthreads();   // protect LDS across reps
  }
}

// =====================================================================
// K2: reduce 4 chunks -> L2-normalized values + invD (to d_ws)
// grid 256 = (b, o-tile), 512 threads
// =====================================================================
__global__ void __launch_bounds__(512) attn_reduce(
    const float* __restrict__ scratch, float* __restrict__ outV,
    float* __restrict__ invD)
{
  __shared__ float R2[8][64];
  __shared__ float Nn[64];

  const int tid = threadIdx.x;
  const int b   = blockIdx.x & 7;
  const int ot  = blockIdx.x >> 3;
  const float* base = scratch + (size_t)(b * 32 + ot) * 4 * SCR_STRIDE;

  const int ol = tid & 63;    // o within tile
  const int vg = tid >> 6;    // v group 0..7

  float u[8];
#pragma unroll
  for (int j = 0; j < 8; ++j) u[j] = 0.f;
#pragma unroll
  for (int c = 0; c < 4; ++c) {
    const float* p = base + c * SCR_STRIDE;
#pragma unroll
    for (int j = 0; j < 8; ++j) u[j] += p[(vg + 8 * j) * 64 + ol];
  }
  float ssq = 0.f;
#pragma unroll
  for (int j = 0; j < 8; ++j) ssq += u[j] * u[j];
  R2[vg][ol] = ssq;
  __syncthreads();
  if (tid < 64) {
    float n = 0.f;
#pragma unroll
    for (int g = 0; g < 8; ++g) n += R2[g][tid];
    Nn[tid] = 1.f / (sqrtf(n) + 1e-12f);
    float D = 0.f;
#pragma unroll
    for (int c = 0; c < 4; ++c) D += base[c * SCR_STRIDE + 4096 + tid];
    invD[b * NN + ot * 64 + tid] = 1.f / D;
  }
  __syncthreads();
  const float inn = Nn[ol];
  float* vp = outV + (size_t)b * VV * NN + ot * 64 + ol;
#pragma unroll
  for (int j = 0; j < 8; ++j)
    vp[(size_t)(vg + 8 * j) * NN] = u[j] * inn;
}

// =====================================================================
// K3: weights = exp(K.Q^T/8) * invD, 128x128 tile per block.
// (REP'd for measurement.)
// =====================================================================
__global__ void __launch_bounds__(256) attn_weights(
    const float* __restrict__ key, const float* __restrict__ query,
    const float* __restrict__ invDp, float* __restrict__ outWall, int z)
{
  __shared__ __align__(16) unsigned short Kt2[128 * 64];

  const int tid  = threadIdx.x;
  const int lane = tid & 63;
  const int wv   = tid >> 6;
  const int l15  = lane & 15;
  const int l4   = lane >> 4;

  const int b    = blockIdx.x & 7;           // batch -> XCD
  const int rest = blockIdx.x >> 3;
  const int it   = rest & 15;                // i-tile (128)
  const int ot   = rest >> 4;                // o-tile (128)

  for (int rep = 0; rep < REP; ++rep) {
    const float* Kg = key   + (size_t)b * NN * KK + (size_t)(rep * z);
    const float* Qg = query + (size_t)b * NN * KK + (size_t)(rep * z);
    const float* invD = invDp + (size_t)(rep * z);
    float* outW = outWall + (size_t)b * NN * NN + (size_t)(rep * z);

    // stage K tile: 128 rows x 64 k, 2 threads/row x 32 floats
    {
      const int krow = tid >> 1;
      const int half = (tid & 1);
      KS sA, sB;
      k_load(sA, Kg + (size_t)(it * 128 + krow) * KK + half * 32);
      k_load(sB, Kg + (size_t)(it * 128 + krow) * KK + half * 32 + 16);
      k_write(sA, Kt2, krow, half * 64);
      k_write(sB, Kt2, krow, half * 64 + 32);
    }

    // Q fragments (A-op: o-row = wv*32 + m*16 + l15), direct from global
    bfrag a0[2], a1[2];
#pragma unroll
    for (int m = 0; m < 2; ++m) {
      const float* qr = Qg + (size_t)(ot * 128 + wv * 32 + m * 16 + l15) * KK;
      a0[m] = g_frag(qr + l4 * 8);
      a1[m] = g_frag(qr + 32 + l4 * 8);
    }
    // invD for this lane's 4 consecutive o, both m blocks
    f32x4 id[2];
#pragma unroll
    for (int m = 0; m < 2; ++m)
      id[m] = *reinterpret_cast<const f32x4*>(
          &invD[b * NN + ot * 128 + wv * 32 + m * 16 + l4 * 4]);
    __syncthreads();

    // MFMA cluster: acc[m][s] over the whole tile, no stores interleaved
    f32x4 acc[2][8];
#pragma unroll
    for (int m = 0; m < 2; ++m)
#pragma unroll
      for (int s = 0; s < 8; ++s) { f32x4 zz = {0.f, 0.f, 0.f, 0.f}; acc[m][s] = zz; }

#pragma unroll
    for (int s = 0; s < 8; ++s) {
      bfrag b0 = lds_frag(Kt2, s * 16 + l15, l4 * 16);
      bfrag b1 = lds_frag(Kt2, s * 16 + l15, 64 + l4 * 16);
#pragma unroll
      for (int m = 0; m < 2; ++m) {
        acc[m][s] = __builtin_amdgcn_mfma_f32_16x16x32_bf16(a0[m], b0, acc[m][s], 0, 0, 0);
        acc[m][s] = __builtin_amdgcn_mfma_f32_16x16x32_bf16(a1[m], b1, acc[m][s], 0, 0, 0);
      }
    }

    // epilogue: exp * invD, f32x4 stores (4 consecutive o per lane)
#pragma unroll
    for (int s = 0; s < 8; ++s)
#pragma unroll
      for (int m = 0; m < 2; ++m) {
        f32x4 w;
#pragma unroll
        for (int r = 0; r < 4; ++r) w[r] = exp2f(acc[m][s][r] * SCALE) * id[m][r];
        float* wp = outW + (size_t)(it * 128 + s * 16 + l15) * NN +
                    ot * 128 + wv * 32 + m * 16 + l4 * 4;
        *reinterpret_cast<f32x4*>(wp) = w;
      }
    __syncthreads();   // protect Kt2 across reps
  }
}

extern "C" void kernel_launch(void* const* d_in, const int* in_sizes, int n_in,
                              void* d_out, int out_size, void* d_ws, size_t ws_size,
                              hipStream_t stream) {
  (void)in_sizes; (void)n_in; (void)ws_size; (void)out_size;
  const float* key   = (const float*)d_in[0];
  const float* query = (const float*)d_in[1];
  const float* value = (const float*)d_in[2];
  float* out  = (float*)d_out;
  float* outV = out;                                  // [B][V][N] values
  float* outW = out + (size_t)NB * VV * NN;           // [B][N][N] weights
  float* invD = (float*)d_ws;                         // 8*2048 floats (64KB)
  float* scratch = outW;                              // K1 partials at head of
                                                      // weights region; K3
                                                      // overwrites after K2.

  attn_pass1 <<<dim3(NB * 32 * 4), dim3(256), 0, stream>>>(key, query, value, scratch, 0);
  attn_reduce<<<dim3(NB * 32),     dim3(512), 0, stream>>>(scratch, outV, invD);
  attn_weights<<<dim3(NB * 16 * 16), dim3(256), 0, stream>>>(key, query, invD, outW, 0);
}

// Round 8
// 90.366 us; speedup vs baseline: 2.1165x; 2.1165x over previous
//
#include <hip/hip_runtime.h>

// Problem constants (fixed by reference)
#define NB 8
#define NN 2048
#define KK 64
#define VV 64
#define SCALE 0.18033688011112043f  // (1/sqrt(64)) * log2(e)

typedef __bf16 bfrag  __attribute__((ext_vector_type(8)));
typedef __bf16 bf16x4 __attribute__((ext_vector_type(4)));
typedef float  f32x4  __attribute__((ext_vector_type(4)));

// LDS byte offset within a tile with 128B rows, XOR-swizzled (G4)
__device__ __forceinline__ int swz(int row, int colByte) {
  return row * 128 + (colByte ^ ((row & 7) << 4));
}

__device__ __forceinline__ bfrag lds_frag(const unsigned short* base, int row, int colByte) {
  return *reinterpret_cast<const bfrag*>(reinterpret_cast<const char*>(base) + swz(row, colByte));
}

// 8 consecutive global fp32 -> bf16 MFMA fragment (v_cvt_pk via plain casts)
__device__ __forceinline__ bfrag g_frag(const float* __restrict__ g) {
  const float4* p = reinterpret_cast<const float4*>(g);
  float4 x = p[0], y = p[1];
  bfrag r;
  r[0] = (__bf16)x.x; r[1] = (__bf16)x.y; r[2] = (__bf16)x.z; r[3] = (__bf16)x.w;
  r[4] = (__bf16)y.x; r[5] = (__bf16)y.y; r[6] = (__bf16)y.z; r[7] = (__bf16)y.w;
  return r;
}

// ---- staging: 16 consecutive fp32 -> 16 bf16 into one LDS row ----
struct KS { float4 f[4]; };
__device__ __forceinline__ void k_load(KS& s, const float* __restrict__ g) {
  const float4* p = reinterpret_cast<const float4*>(g);
  s.f[0] = p[0]; s.f[1] = p[1]; s.f[2] = p[2]; s.f[3] = p[3];
}
__device__ __forceinline__ void k_write(const KS& s, unsigned short* lds, int row, int colByte) {
  const float* f = reinterpret_cast<const float*>(&s.f[0]);
  bfrag a, b;
#pragma unroll
  for (int j = 0; j < 8; ++j) a[j] = (__bf16)f[j];
#pragma unroll
  for (int j = 0; j < 8; ++j) b[j] = (__bf16)f[8 + j];
  *reinterpret_cast<bfrag*>(reinterpret_cast<char*>(lds) + swz(row, colByte)) = a;
  *reinterpret_cast<bfrag*>(reinterpret_cast<char*>(lds) + swz(row, colByte + 16)) = b;
}

// ---- V staging: rows (il, il+1) x 8 v -> transposed Vt[v][i] ----
struct VS { float4 f[4]; };
__device__ __forceinline__ void v_load(VS& s, const float* __restrict__ g) {
  const float4* p = reinterpret_cast<const float4*>(g);
  s.f[0] = p[0]; s.f[1] = p[1];
  const float4* q = reinterpret_cast<const float4*>(g + VV);
  s.f[2] = q[0]; s.f[3] = q[1];
}
__device__ __forceinline__ void v_write(const VS& s, unsigned short* lds, int il, int v0) {
  const float* lo = reinterpret_cast<const float*>(&s.f[0]);
  const float* hi = reinterpret_cast<const float*>(&s.f[2]);
#pragma unroll
  for (int j = 0; j < 8; ++j) {
    __bf16 two[2] = { (__bf16)lo[j], (__bf16)hi[j] };
    *reinterpret_cast<unsigned*>(reinterpret_cast<char*>(lds) + swz(v0 + j, il * 2)) =
        *reinterpret_cast<unsigned*>(two);
  }
}

// =====================================================================
// K1 (rebuilt): per (b, o-tile 64, i-chunk 512): partial D[64] and
// partial U[64][64] -> scratch.
//   wave w: i-half = w&1 (32 i/step), o-half = w>>1 (32 o).
//   K rows loaded QUAD-INTERLEAVED direct from global: z1 <- even quads,
//   z2 <- odd quads  =>  lane's (z1,z2) = E[i = l4*8+{0..7}][o=l15]
//   which IS the PV B-fragment. E never touches LDS; no K LDS; only V
//   staged (dbuf, ONE barrier/step). Cross-wave U reduce once at end.
// =====================================================================
#define CHUNK 512
#define K1STEPS (CHUNK / 64)   // 8
#define SCR_STRIDE 4160        // 64*64 U + 64 D floats per chunk

__global__ void __launch_bounds__(256, 4) attn_pass1(
    const float* __restrict__ key, const float* __restrict__ query,
    const float* __restrict__ value, float* __restrict__ scratch)
{
  // Vt[2] (2 x 8192B) overlaid (after last PV) with Ured[64][65] f32 (16640B)
  __shared__ __align__(16) char smem[16640];
  __shared__ float Red[4][32];
  unsigned short* Vt0 = reinterpret_cast<unsigned short*>(smem);
  unsigned short* Vt1 = reinterpret_cast<unsigned short*>(smem + 8192);
  float* Ured = reinterpret_cast<float*>(smem);

  const int tid  = threadIdx.x;
  const int lane = tid & 63;
  const int w    = tid >> 6;
  const int l15  = lane & 15;
  const int l4   = lane >> 4;
  const int ihalf = w & 1;     // which 32-i half of the step
  const int ohalf = w >> 1;    // which 32-o half of the tile

  const int b    = blockIdx.x & 7;          // batch -> XCD
  const int rest = blockIdx.x >> 3;
  const int ot   = rest & 31;               // o-tile (64)
  const int ci   = rest >> 5;               // i-chunk (512)
  const int o0   = ot * 64;
  const int ib0  = ci * CHUNK;

  const float* Kg = key   + (size_t)b * NN * KK;
  const float* Qg = query + (size_t)b * NN * KK;
  const float* Vg = value + (size_t)b * NN * VV;
  float* scr = scratch + (size_t)((b * 32 + ot) * 4 + ci) * SCR_STRIDE;

  // Q fragments (B-op: o-slot = l15), direct from global, loaded once
  bfrag qb[2][2];
#pragma unroll
  for (int s = 0; s < 2; ++s) {
    const float* qr = Qg + (size_t)(o0 + ohalf * 32 + s * 16 + l15) * KK;
    qb[s][0] = g_frag(qr + l4 * 8);
    qb[s][1] = g_frag(qr + 32 + l4 * 8);
  }

  // quad-interleaved K row permutation: slot p -> i = (p&3) + 8*(p>>2)
  const int iperm = (l15 & 3) + ((l15 >> 2) * 8);

  // V staging coords (256 threads stage 64 i x 64 v)
  const int vil = (tid & 31) * 2;
  const int vv0 = (tid >> 5) * 8;

  VS vs;
  v_load(vs, Vg + (size_t)(ib0 + vil) * VV + vv0);
  v_write(vs, Vt0, vil, vv0);
  __syncthreads();

  f32x4 uacc[4][2];
#pragma unroll
  for (int vc = 0; vc < 4; ++vc)
#pragma unroll
    for (int s = 0; s < 2; ++s) { f32x4 z = {0.f,0.f,0.f,0.f}; uacc[vc][s] = z; }
  float Dacc[2] = {0.f, 0.f};

  for (int t = 0; t < K1STEPS; ++t) {
    unsigned short* Vcur = (t & 1) ? Vt1 : Vt0;
    unsigned short* Vnxt = (t & 1) ? Vt0 : Vt1;
    if (t + 1 < K1STEPS)
      v_load(vs, Vg + (size_t)(ib0 + (t + 1) * 64 + vil) * VV + vv0);

    const int ibase = ib0 + t * 64 + ihalf * 32;
    const float* kr1 = Kg + (size_t)(ibase + iperm) * KK;       // even quads
    const float* kr2 = Kg + (size_t)(ibase + iperm + 4) * KK;   // odd quads
    bfrag ka10 = g_frag(kr1 + l4 * 8), ka11 = g_frag(kr1 + 32 + l4 * 8);
    bfrag ka20 = g_frag(kr2 + l4 * 8), ka21 = g_frag(kr2 + 32 + l4 * 8);

    // QK + exp -> PV B-fragments, fully in-register
    bfrag eb[2];
#pragma unroll
    for (int s = 0; s < 2; ++s) {
      f32x4 z1 = {0.f,0.f,0.f,0.f}, z2 = {0.f,0.f,0.f,0.f};
      z1 = __builtin_amdgcn_mfma_f32_16x16x32_bf16(ka10, qb[s][0], z1, 0, 0, 0);
      z1 = __builtin_amdgcn_mfma_f32_16x16x32_bf16(ka11, qb[s][1], z1, 0, 0, 0);
      z2 = __builtin_amdgcn_mfma_f32_16x16x32_bf16(ka20, qb[s][0], z2, 0, 0, 0);
      z2 = __builtin_amdgcn_mfma_f32_16x16x32_bf16(ka21, qb[s][1], z2, 0, 0, 0);
      f32x4 e1, e2;
#pragma unroll
      for (int r = 0; r < 4; ++r) e1[r] = exp2f(z1[r] * SCALE);
#pragma unroll
      for (int r = 0; r < 4; ++r) e2[r] = exp2f(z2[r] * SCALE);
      Dacc[s] += e1[0] + e1[1] + e1[2] + e1[3] + e2[0] + e2[1] + e2[2] + e2[3];
      bfrag e;
#pragma unroll
      for (int r = 0; r < 4; ++r) e[r]     = (__bf16)e1[r];   // i = l4*8 + r
#pragma unroll
      for (int r = 0; r < 4; ++r) e[4 + r] = (__bf16)e2[r];   // i = l4*8 + 4 + r
      eb[s] = e;
    }

    // PV: U[v][o] += V^T . E over this wave's 32 i (one K=32 MFMA per vc,s)
    bfrag va[4];
#pragma unroll
    for (int vc = 0; vc < 4; ++vc)
      va[vc] = lds_frag(Vcur, vc * 16 + l15, ihalf * 64 + l4 * 16);
#pragma unroll
    for (int vc = 0; vc < 4; ++vc)
#pragma unroll
      for (int s = 0; s < 2; ++s)
        uacc[vc][s] = __builtin_amdgcn_mfma_f32_16x16x32_bf16(va[vc], eb[s], uacc[vc][s], 0, 0, 0);

    if (t + 1 < K1STEPS) v_write(vs, Vnxt, vil, vv0);
    __syncthreads();   // Vnxt ready; Vcur reads done (safe to overwrite next)
  }

  // ---- D partial: reduce over l4 then across the 2 i-half waves ----
#pragma unroll
  for (int s = 0; s < 2; ++s) {
    float d = Dacc[s];
    d += __shfl_xor(d, 16, 64);
    d += __shfl_xor(d, 32, 64);
    if (lane < 16) Red[w][s * 16 + lane] = d;
  }

  // ---- U partial: 2-way cross-wave reduce in LDS (overlay on Vt) ----
  if (ihalf == 0) {
#pragma unroll
    for (int vc = 0; vc < 4; ++vc)
#pragma unroll
      for (int s = 0; s < 2; ++s)
#pragma unroll
        for (int r = 0; r < 4; ++r)
          Ured[(vc * 16 + l4 * 4 + r) * 65 + ohalf * 32 + s * 16 + l15] = uacc[vc][s][r];
  }
  __syncthreads();
  if (ihalf == 1) {
#pragma unroll
    for (int vc = 0; vc < 4; ++vc)
#pragma unroll
      for (int s = 0; s < 2; ++s)
#pragma unroll
        for (int r = 0; r < 4; ++r)
          Ured[(vc * 16 + l4 * 4 + r) * 65 + ohalf * 32 + s * 16 + l15] += uacc[vc][s][r];
  }
  if (tid < 64) {
    const int oh = tid >> 5, ol = tid & 31;
    scr[4096 + tid] = Red[oh * 2][ol] + Red[oh * 2 + 1][ol];
  }
  __syncthreads();
#pragma unroll
  for (int j = 0; j < 16; ++j) {
    const int idx = j * 256 + tid;
    scr[idx] = Ured[(idx >> 6) * 65 + (idx & 63)];
  }
}

// =====================================================================
// K2: reduce 4 chunks -> L2-normalized values + invD (to d_ws)
// grid 256 = (b, o-tile), 512 threads
// =====================================================================
__global__ void __launch_bounds__(512) attn_reduce(
    const float* __restrict__ scratch, float* __restrict__ outV,
    float* __restrict__ invD)
{
  __shared__ float R2[8][64];
  __shared__ float Nn[64];

  const int tid = threadIdx.x;
  const int b   = blockIdx.x & 7;
  const int ot  = blockIdx.x >> 3;
  const float* base = scratch + (size_t)(b * 32 + ot) * 4 * SCR_STRIDE;

  const int ol = tid & 63;    // o within tile
  const int vg = tid >> 6;    // v group 0..7

  float u[8];
#pragma unroll
  for (int j = 0; j < 8; ++j) u[j] = 0.f;
#pragma unroll
  for (int c = 0; c < 4; ++c) {
    const float* p = base + c * SCR_STRIDE;
#pragma unroll
    for (int j = 0; j < 8; ++j) u[j] += p[(vg + 8 * j) * 64 + ol];
  }
  float ssq = 0.f;
#pragma unroll
  for (int j = 0; j < 8; ++j) ssq += u[j] * u[j];
  R2[vg][ol] = ssq;
  __syncthreads();
  if (tid < 64) {
    float n = 0.f;
#pragma unroll
    for (int g = 0; g < 8; ++g) n += R2[g][tid];
    Nn[tid] = 1.f / (sqrtf(n) + 1e-12f);
    float D = 0.f;
#pragma unroll
    for (int c = 0; c < 4; ++c) D += base[c * SCR_STRIDE + 4096 + tid];
    invD[b * NN + ot * 64 + tid] = 1.f / D;
  }
  __syncthreads();
  const float inn = Nn[ol];
  float* vp = outV + (size_t)b * VV * NN + ot * 64 + ol;
#pragma unroll
  for (int j = 0; j < 8; ++j)
    vp[(size_t)(vg + 8 * j) * NN] = u[j] * inn;
}

// =====================================================================
// K3: weights = exp(K.Q^T/8) * invD, 128x128 tile per block.
// A = Q (direct-global wave-private frags), B = K (LDS, shared x4 waves).
// MFMA cluster then f32x4 store-burst epilogue. 16KB LDS.
// =====================================================================
__global__ void __launch_bounds__(256) attn_weights(
    const float* __restrict__ key, const float* __restrict__ query,
    const float* __restrict__ invD, float* __restrict__ outWall)
{
  __shared__ __align__(16) unsigned short Kt2[128 * 64];

  const int tid  = threadIdx.x;
  const int lane = tid & 63;
  const int wv   = tid >> 6;
  const int l15  = lane & 15;
  const int l4   = lane >> 4;

  const int b    = blockIdx.x & 7;           // batch -> XCD
  const int rest = blockIdx.x >> 3;
  const int it   = rest & 15;                // i-tile (128)
  const int ot   = rest >> 4;                // o-tile (128)

  const float* Kg = key   + (size_t)b * NN * KK;
  const float* Qg = query + (size_t)b * NN * KK;
  float* outW = outWall + (size_t)b * NN * NN;

  // stage K tile: 128 rows x 64 k, 2 threads/row x 32 floats
  {
    const int krow = tid >> 1;
    const int half = (tid & 1);
    KS sA, sB;
    k_load(sA, Kg + (size_t)(it * 128 + krow) * KK + half * 32);
    k_load(sB, Kg + (size_t)(it * 128 + krow) * KK + half * 32 + 16);
    k_write(sA, Kt2, krow, half * 64);
    k_write(sB, Kt2, krow, half * 64 + 32);
  }

  // Q fragments (A-op: o-row = wv*32 + m*16 + l15), direct from global
  bfrag a0[2], a1[2];
#pragma unroll
  for (int m = 0; m < 2; ++m) {
    const float* qr = Qg + (size_t)(ot * 128 + wv * 32 + m * 16 + l15) * KK;
    a0[m] = g_frag(qr + l4 * 8);
    a1[m] = g_frag(qr + 32 + l4 * 8);
  }
  // invD for this lane's 4 consecutive o, both m blocks
  f32x4 id[2];
#pragma unroll
  for (int m = 0; m < 2; ++m)
    id[m] = *reinterpret_cast<const f32x4*>(
        &invD[b * NN + ot * 128 + wv * 32 + m * 16 + l4 * 4]);
  __syncthreads();

  // MFMA cluster: acc[m][s] over the whole tile, no stores interleaved
  f32x4 acc[2][8];
#pragma unroll
  for (int m = 0; m < 2; ++m)
#pragma unroll
    for (int s = 0; s < 8; ++s) { f32x4 z = {0.f,0.f,0.f,0.f}; acc[m][s] = z; }

#pragma unroll
  for (int s = 0; s < 8; ++s) {
    bfrag b0 = lds_frag(Kt2, s * 16 + l15, l4 * 16);
    bfrag b1 = lds_frag(Kt2, s * 16 + l15, 64 + l4 * 16);
#pragma unroll
    for (int m = 0; m < 2; ++m) {
      acc[m][s] = __builtin_amdgcn_mfma_f32_16x16x32_bf16(a0[m], b0, acc[m][s], 0, 0, 0);
      acc[m][s] = __builtin_amdgcn_mfma_f32_16x16x32_bf16(a1[m], b1, acc[m][s], 0, 0, 0);
    }
  }

  // epilogue: exp * invD, f32x4 stores (4 consecutive o per lane)
#pragma unroll
  for (int s = 0; s < 8; ++s)
#pragma unroll
    for (int m = 0; m < 2; ++m) {
      f32x4 w;
#pragma unroll
      for (int r = 0; r < 4; ++r) w[r] = exp2f(acc[m][s][r] * SCALE) * id[m][r];
      float* wp = outW + (size_t)(it * 128 + s * 16 + l15) * NN +
                  ot * 128 + wv * 32 + m * 16 + l4 * 4;
      *reinterpret_cast<f32x4*>(wp) = w;
    }
}

extern "C" void kernel_launch(void* const* d_in, const int* in_sizes, int n_in,
                              void* d_out, int out_size, void* d_ws, size_t ws_size,
                              hipStream_t stream) {
  (void)in_sizes; (void)n_in; (void)ws_size; (void)out_size;
  const float* key   = (const float*)d_in[0];
  const float* query = (const float*)d_in[1];
  const float* value = (const float*)d_in[2];
  float* out  = (float*)d_out;
  float* outV = out;                                  // [B][V][N] values
  float* outW = out + (size_t)NB * VV * NN;           // [B][N][N] weights
  float* invD = (float*)d_ws;                         // 8*2048 floats (64KB)
  float* scratch = outW;                              // K1 partials at head of
                                                      // weights region; K3
                                                      // overwrites after K2.

  attn_pass1 <<<dim3(NB * 32 * 4), dim3(256), 0, stream>>>(key, query, value, scratch);
  attn_reduce<<<dim3(NB * 32),     dim3(512), 0, stream>>>(scratch, outV, invD);
  attn_weights<<<dim3(NB * 16 * 16), dim3(256), 0, stream>>>(key, query, invD, outW);
}

// Round 9
// 78.700 us; speedup vs baseline: 2.4303x; 1.1482x over previous
//
#include <hip/hip_runtime.h>

// Problem constants (fixed by reference)
#define NB 8
#define NN 2048
#define KK 64
#define VV 64
#define OS 32                       // o-stripe per block
#define NT 32                       // i-steps of 64 (2048/64)
#define SCALE 0.18033688011112043f  // (1/sqrt(64)) * log2(e)
#define USTRIDE 36                  // U-reduce LDS row stride (floats)

typedef __bf16 bfrag __attribute__((ext_vector_type(8)));
typedef float  f32x4 __attribute__((ext_vector_type(4)));

// LDS byte offset within a 64x64-bf16 tile (128B rows), XOR-swizzled (G4)
__device__ __forceinline__ int swz(int row, int colByte) {
  return row * 128 + (colByte ^ ((row & 7) << 4));
}

__device__ __forceinline__ bfrag lds_frag(const unsigned short* base, int row, int colByte) {
  return *reinterpret_cast<const bfrag*>(reinterpret_cast<const char*>(base) + swz(row, colByte));
}

// 8 consecutive global fp32 -> bf16 MFMA fragment (v_cvt_pk via plain casts)
__device__ __forceinline__ bfrag g_frag(const float* __restrict__ g) {
  const float4* p = reinterpret_cast<const float4*>(g);
  float4 x = p[0], y = p[1];
  bfrag r;
  r[0] = (__bf16)x.x; r[1] = (__bf16)x.y; r[2] = (__bf16)x.z; r[3] = (__bf16)x.w;
  r[4] = (__bf16)y.x; r[5] = (__bf16)y.y; r[6] = (__bf16)y.z; r[7] = (__bf16)y.w;
  return r;
}

// ---- K staging: 16 consecutive fp32 -> 16 bf16 into one LDS row ----
struct KS { float4 f[4]; };
__device__ __forceinline__ void k_load(KS& s, const float* __restrict__ g) {
  const float4* p = reinterpret_cast<const float4*>(g);
  s.f[0] = p[0]; s.f[1] = p[1]; s.f[2] = p[2]; s.f[3] = p[3];
}
__device__ __forceinline__ void k_write(const KS& s, unsigned short* lds, int row, int colByte) {
  const float* f = reinterpret_cast<const float*>(&s.f[0]);
  bfrag a, b;
#pragma unroll
  for (int j = 0; j < 8; ++j) a[j] = (__bf16)f[j];
#pragma unroll
  for (int j = 0; j < 8; ++j) b[j] = (__bf16)f[8 + j];
  *reinterpret_cast<bfrag*>(reinterpret_cast<char*>(lds) + swz(row, colByte)) = a;
  *reinterpret_cast<bfrag*>(reinterpret_cast<char*>(lds) + swz(row, colByte + 16)) = b;
}

// ---- V staging: rows (il, il+1) x 8 v -> transposed Vt[v][i] ----
struct VS { float4 f[4]; };
__device__ __forceinline__ void v_load(VS& s, const float* __restrict__ g) {
  const float4* p = reinterpret_cast<const float4*>(g);
  s.f[0] = p[0]; s.f[1] = p[1];
  const float4* q = reinterpret_cast<const float4*>(g + VV);
  s.f[2] = q[0]; s.f[3] = q[1];
}
__device__ __forceinline__ void v_write(const VS& s, unsigned short* lds, int il, int v0) {
  const float* lo = reinterpret_cast<const float*>(&s.f[0]);
  const float* hi = reinterpret_cast<const float*>(&s.f[2]);
#pragma unroll
  for (int j = 0; j < 8; ++j) {
    __bf16 two[2] = { (__bf16)lo[j], (__bf16)hi[j] };
    *reinterpret_cast<unsigned*>(reinterpret_cast<char*>(lds) + swz(v0 + j, il * 2)) =
        *reinterpret_cast<unsigned*>(two);
  }
}

// =====================================================================
// Fully fused kernel. Block = (b, o-stripe 32). 512 threads (8 waves).
// Pass A: D[32] + U[64][32] over all i (K/V dbuf LDS, in-register E).
// Epilogue: U reduce, L2-norm -> values; invD.
// Pass B: recompute scores, write weights = exp * invD (f32x4 stores).
// =====================================================================
__global__ void __launch_bounds__(512, 4) attn_fused(
    const float* __restrict__ key, const float* __restrict__ query,
    const float* __restrict__ value, float* __restrict__ out)
{
  __shared__ __align__(16) char smem[32768];
  __shared__ float Red[4][16];
  __shared__ float InvD[OS];
  __shared__ float Nn[OS];
  unsigned short* Kt0 = reinterpret_cast<unsigned short*>(smem);
  unsigned short* Kt1 = reinterpret_cast<unsigned short*>(smem + 8192);
  unsigned short* Vt0 = reinterpret_cast<unsigned short*>(smem + 16384);
  unsigned short* Vt1 = reinterpret_cast<unsigned short*>(smem + 24576);
  float* U0 = reinterpret_cast<float*>(smem);          // 64*36*4 = 9216B
  float* U1 = reinterpret_cast<float*>(smem + 9216);   // 9216B

  const int tid  = threadIdx.x;
  const int lane = tid & 63;
  const int w    = tid >> 6;      // wave 0..7
  const int l15  = lane & 15;
  const int l4   = lane >> 4;
  const int vhalf = w & 1;        // v-half (PV)
  const int ihalf = (w >> 1) & 1; // i-half of each 64-i step
  const int oh    = w >> 2;       // o-half of the 32-o stripe

  const int b  = blockIdx.x & 7;          // batch -> XCD
  const int o0 = (blockIdx.x >> 3) * OS;  // o-stripe base

  const float* Kg = key   + (size_t)b * NN * KK;
  const float* Qg = query + (size_t)b * NN * KK;
  const float* Vg = value + (size_t)b * NN * VV;
  float* outV = out + (size_t)b * VV * NN;
  float* outW = out + (size_t)NB * VV * NN + (size_t)b * NN * NN;

  // Q fragments: lane l15 = o-row (oh group), k = l4*8+j. Serves as
  // B-operand in pass A and A-operand in pass B (identical lane layout).
  bfrag qb0, qb1;
  {
    const float* qr = Qg + (size_t)(o0 + oh * 16 + l15) * KK;
    qb0 = g_frag(qr + l4 * 8);
    qb1 = g_frag(qr + 32 + l4 * 8);
  }

  // pass-A staging coords: waves 0-3 stage K, waves 4-7 stage V
  const int krow = tid >> 2;           // 0..63 (tid<256)
  const int kel  = (tid & 3) * 16;
  const int kcb  = (tid & 3) * 32;
  const int t2   = tid & 255;
  const int vil  = (t2 & 31) * 2;
  const int vv0  = (t2 >> 5) * 8;

  KS ks; VS vs;
  if (tid < 256) { k_load(ks, Kg + (size_t)krow * KK + kel); }
  else           { v_load(vs, Vg + (size_t)vil * VV + vv0); }
  if (tid < 256) k_write(ks, Kt0, krow, kcb);
  else           v_write(vs, Vt0, vil, vv0);
  __syncthreads();

  // quad-interleaved A-row permutation: slot p -> i = (p&3) + 8*(p>>2)
  const int ip = (l15 & 3) + ((l15 >> 2) * 8);

  f32x4 uacc[2];
  { f32x4 z = {0.f,0.f,0.f,0.f}; uacc[0] = z; uacc[1] = z; }
  float Dacc = 0.f;

  // ================= PASS A =================
  for (int t = 0; t < NT; ++t) {
    unsigned short* Kc = (t & 1) ? Kt1 : Kt0;
    unsigned short* Vc = (t & 1) ? Vt1 : Vt0;
    unsigned short* Kn = (t & 1) ? Kt0 : Kt1;
    unsigned short* Vn = (t & 1) ? Vt0 : Vt1;
    if (t + 1 < NT) {
      if (tid < 256) k_load(ks, Kg + (size_t)((t + 1) * 64 + krow) * KK + kel);
      else           v_load(vs, Vg + (size_t)((t + 1) * 64 + vil) * VV + vv0);
    }
    // QK: A = K rows (quad-interleaved), B = Q. Lane gets E at
    // (i = l4*8 + 0..7, o = l15) -> the PV B-fragment, in-register.
    const int r1 = ihalf * 32 + ip;
    bfrag ka10 = lds_frag(Kc, r1,     l4 * 16);
    bfrag ka11 = lds_frag(Kc, r1,     64 + l4 * 16);
    bfrag ka20 = lds_frag(Kc, r1 + 4, l4 * 16);
    bfrag ka21 = lds_frag(Kc, r1 + 4, 64 + l4 * 16);
    f32x4 z1 = {0.f,0.f,0.f,0.f}, z2 = {0.f,0.f,0.f,0.f};
    z1 = __builtin_amdgcn_mfma_f32_16x16x32_bf16(ka10, qb0, z1, 0, 0, 0);
    z1 = __builtin_amdgcn_mfma_f32_16x16x32_bf16(ka11, qb1, z1, 0, 0, 0);
    z2 = __builtin_amdgcn_mfma_f32_16x16x32_bf16(ka20, qb0, z2, 0, 0, 0);
    z2 = __builtin_amdgcn_mfma_f32_16x16x32_bf16(ka21, qb1, z2, 0, 0, 0);
    f32x4 e1, e2;
#pragma unroll
    for (int r = 0; r < 4; ++r) e1[r] = exp2f(z1[r] * SCALE);
#pragma unroll
    for (int r = 0; r < 4; ++r) e2[r] = exp2f(z2[r] * SCALE);
    Dacc += e1[0] + e1[1] + e1[2] + e1[3] + e2[0] + e2[1] + e2[2] + e2[3];
    bfrag eb;
#pragma unroll
    for (int r = 0; r < 4; ++r) eb[r]     = (__bf16)e1[r];
#pragma unroll
    for (int r = 0; r < 4; ++r) eb[4 + r] = (__bf16)e2[r];
    // PV: U[v][o] += V^T.E over this wave's 32 i
#pragma unroll
    for (int vg = 0; vg < 2; ++vg) {
      bfrag va = lds_frag(Vc, vhalf * 32 + vg * 16 + l15, ihalf * 64 + l4 * 16);
      uacc[vg] = __builtin_amdgcn_mfma_f32_16x16x32_bf16(va, eb, uacc[vg], 0, 0, 0);
    }
    if (t + 1 < NT) {
      if (tid < 256) k_write(ks, Kn, krow, kcb);
      else           v_write(vs, Vn, vil, vv0);
    }
    __syncthreads();
  }

  // ---- D partial (dup across vhalf; only vhalf==0 writes) ----
  {
    float d = Dacc;
    d += __shfl_xor(d, 16, 64);
    d += __shfl_xor(d, 32, 64);
    if ((w & 1) == 0 && lane < 16) Red[w >> 1][lane] = d;  // rid = oh*2+ihalf
  }
  // ---- U partials -> LDS (overlay staging; stride-36 rows) ----
  {
    float* Ur = ihalf ? U1 : U0;
#pragma unroll
    for (int vg = 0; vg < 2; ++vg)
#pragma unroll
      for (int r = 0; r < 4; ++r)
        Ur[(vhalf * 32 + vg * 16 + l4 * 4 + r) * USTRIDE + oh * 16 + l15] = uacc[vg][r];
  }
  __syncthreads();
  // combine the 2 i-halves (512 threads x 4 floats, in-place into U0)
  {
    const int v = tid >> 3, o = (tid & 7) * 4;
    f32x4 a = *reinterpret_cast<f32x4*>(&U0[v * USTRIDE + o]);
    f32x4 c = *reinterpret_cast<f32x4*>(&U1[v * USTRIDE + o]);
    a = a + c;
    *reinterpret_cast<f32x4*>(&U0[v * USTRIDE + o]) = a;
  }
  __syncthreads();
  if (tid < OS) {
    float ssq = 0.f;
#pragma unroll
    for (int v = 0; v < VV; ++v) { float x = U0[v * USTRIDE + tid]; ssq += x * x; }
    Nn[tid] = 1.f / (sqrtf(ssq) + 1e-12f);
  } else if (tid < 2 * OS) {
    const int o = tid - OS, ohh = o >> 4;
    InvD[o] = 1.f / (Red[ohh * 2][o & 15] + Red[ohh * 2 + 1][o & 15]);
  }
  __syncthreads();
  // values: out[b][v][o0+o], L2-normalized (softmax denom cancels)
  {
    const int v = tid >> 3, o = (tid & 7) * 4;
    f32x4 a  = *reinterpret_cast<f32x4*>(&U0[v * USTRIDE + o]);
    f32x4 nn = *reinterpret_cast<f32x4*>(&Nn[o]);
    f32x4 r;
#pragma unroll
    for (int j = 0; j < 4; ++j) r[j] = a[j] * nn[j];
    *reinterpret_cast<f32x4*>(&outV[(size_t)v * NN + o0 + o]) = r;
  }
  // invD for this lane's pass-B output columns
  f32x4 id = *reinterpret_cast<f32x4*>(&InvD[oh * 16 + l4 * 4]);
  __syncthreads();   // U0 reads done before pass-B staging clobbers smem

  // ================= PASS B: weights =================
  const int iq    = w & 3;        // i-quarter tile (oh stays = w>>2)
  const int kbrow = tid >> 3;     // 0..63
  const int kseg  = tid & 7;      // 8-float segment
  {
    const float4* kp = reinterpret_cast<const float4*>(Kg + (size_t)kbrow * KK + kseg * 8);
    float4 p0 = kp[0], p1 = kp[1];
    bfrag f;
    f[0] = (__bf16)p0.x; f[1] = (__bf16)p0.y; f[2] = (__bf16)p0.z; f[3] = (__bf16)p0.w;
    f[4] = (__bf16)p1.x; f[5] = (__bf16)p1.y; f[6] = (__bf16)p1.z; f[7] = (__bf16)p1.w;
    *reinterpret_cast<bfrag*>(reinterpret_cast<char*>(Kt0) + swz(kbrow, kseg * 16)) = f;
  }
  __syncthreads();
  for (int t = 0; t < NT; ++t) {
    unsigned short* Kc = (t & 1) ? Kt1 : Kt0;
    unsigned short* Kn = (t & 1) ? Kt0 : Kt1;
    float4 p0, p1;
    if (t + 1 < NT) {
      const float4* kp = reinterpret_cast<const float4*>(
          Kg + (size_t)((t + 1) * 64 + kbrow) * KK + kseg * 8);
      p0 = kp[0]; p1 = kp[1];
    }
    // A = Q (o rows), B = K (i cols): lane's 4 outputs = 4 consecutive o
    bfrag kb0 = lds_frag(Kc, iq * 16 + l15, l4 * 16);
    bfrag kb1 = lds_frag(Kc, iq * 16 + l15, 64 + l4 * 16);
    f32x4 z = {0.f,0.f,0.f,0.f};
    z = __builtin_amdgcn_mfma_f32_16x16x32_bf16(qb0, kb0, z, 0, 0, 0);
    z = __builtin_amdgcn_mfma_f32_16x16x32_bf16(qb1, kb1, z, 0, 0, 0);
    f32x4 ww;
#pragma unroll
    for (int r = 0; r < 4; ++r) ww[r] = exp2f(z[r] * SCALE) * id[r];
    float* wp = outW + (size_t)(t * 64 + iq * 16 + l15) * NN + o0 + oh * 16 + l4 * 4;
    *reinterpret_cast<f32x4*>(wp) = ww;
    if (t + 1 < NT) {
      bfrag f;
      f[0] = (__bf16)p0.x; f[1] = (__bf16)p0.y; f[2] = (__bf16)p0.z; f[3] = (__bf16)p0.w;
      f[4] = (__bf16)p1.x; f[5] = (__bf16)p1.y; f[6] = (__bf16)p1.z; f[7] = (__bf16)p1.w;
      *reinterpret_cast<bfrag*>(reinterpret_cast<char*>(Kn) + swz(kbrow, kseg * 16)) = f;
    }
    __syncthreads();
  }
}

extern "C" void kernel_launch(void* const* d_in, const int* in_sizes, int n_in,
                              void* d_out, int out_size, void* d_ws, size_t ws_size,
                              hipStream_t stream) {
  (void)in_sizes; (void)n_in; (void)d_ws; (void)ws_size; (void)out_size;
  const float* key   = (const float*)d_in[0];
  const float* query = (const float*)d_in[1];
  const float* value = (const float*)d_in[2];
  float* out = (float*)d_out;
  attn_fused<<<dim3(NB * (NN / OS)), dim3(512), 0, stream>>>(key, query, value, out);
}

// Round 10
// 78.679 us; speedup vs baseline: 2.4309x; 1.0003x over previous
//
#include <hip/hip_runtime.h>

// Problem constants (fixed by reference)
#define NB 8
#define NN 2048
#define KK 64
#define VV 64
#define OS 64                       // o-stripe per block
#define ITEP 128                    // i per pass-A step
#define NTA (NN / ITEP)             // 16
#define SCALE 0.18033688011112043f  // (1/sqrt(64)) * log2(e)
#define UST 68                      // Ured row stride (floats)

typedef __bf16 bfrag __attribute__((ext_vector_type(8)));
typedef float  f32x4 __attribute__((ext_vector_type(4)));

// K-tile swizzle: 128B rows. XOR key from row bits {0,1,3} so the
// quad-interleaved frag read (rows (l15&3)+8*(l15>>2)) spreads uniformly
// (2 lanes/bank = free) instead of 4-way under (row&7).
__device__ __forceinline__ int swzK(int row, int colByte) {
  const int key = ((row & 3) << 1) | ((row >> 3) & 1);
  return row * 128 + (colByte ^ (key << 4));
}
// V-tile swizzle: 256B rows (64 v x 128 i bf16)
__device__ __forceinline__ int swzV(int row, int colByte) {
  return row * 256 + (colByte ^ ((row & 7) << 4));
}

__device__ __forceinline__ bfrag kfrag(const unsigned short* base, int row, int colByte) {
  return *reinterpret_cast<const bfrag*>(
      reinterpret_cast<const char*>(base) + swzK(row, colByte));
}
__device__ __forceinline__ bfrag vfrag(const unsigned short* base, int row, int colByte) {
  return *reinterpret_cast<const bfrag*>(
      reinterpret_cast<const char*>(base) + swzV(row, colByte));
}

// 8 consecutive global fp32 -> bf16 MFMA fragment (v_cvt_pk via plain casts)
__device__ __forceinline__ bfrag g_frag(const float* __restrict__ g) {
  const float4* p = reinterpret_cast<const float4*>(g);
  float4 x = p[0], y = p[1];
  bfrag r;
  r[0] = (__bf16)x.x; r[1] = (__bf16)x.y; r[2] = (__bf16)x.z; r[3] = (__bf16)x.w;
  r[4] = (__bf16)y.x; r[5] = (__bf16)y.y; r[6] = (__bf16)y.z; r[7] = (__bf16)y.w;
  return r;
}

// ---- K staging: 16 consecutive fp32 -> 16 bf16 into one K-tile row ----
struct KS { float4 f[4]; };
__device__ __forceinline__ void k_load(KS& s, const float* __restrict__ g) {
  const float4* p = reinterpret_cast<const float4*>(g);
  s.f[0] = p[0]; s.f[1] = p[1]; s.f[2] = p[2]; s.f[3] = p[3];
}
__device__ __forceinline__ void k_write(const KS& s, unsigned short* lds, int row, int colByte) {
  const float* f = reinterpret_cast<const float*>(&s.f[0]);
  bfrag a, b;
#pragma unroll
  for (int j = 0; j < 8; ++j) a[j] = (__bf16)f[j];
#pragma unroll
  for (int j = 0; j < 8; ++j) b[j] = (__bf16)f[8 + j];
  *reinterpret_cast<bfrag*>(reinterpret_cast<char*>(lds) + swzK(row, colByte)) = a;
  *reinterpret_cast<bfrag*>(reinterpret_cast<char*>(lds) + swzK(row, colByte + 16)) = b;
}

// ---- V staging: rows (il, il+1) x 8 v -> transposed Vt[v][i] ----
struct VS { float4 f[4]; };
__device__ __forceinline__ void v_load(VS& s, const float* __restrict__ g) {
  const float4* p = reinterpret_cast<const float4*>(g);
  s.f[0] = p[0]; s.f[1] = p[1];
  const float4* q = reinterpret_cast<const float4*>(g + VV);
  s.f[2] = q[0]; s.f[3] = q[1];
}
__device__ __forceinline__ void v_write(const VS& s, unsigned short* lds, int il, int v0) {
  const float* lo = reinterpret_cast<const float*>(&s.f[0]);
  const float* hi = reinterpret_cast<const float*>(&s.f[2]);
#pragma unroll
  for (int j = 0; j < 8; ++j) {
    __bf16 two[2] = { (__bf16)lo[j], (__bf16)hi[j] };
    *reinterpret_cast<unsigned*>(reinterpret_cast<char*>(lds) + swzV(v0 + j, il * 2)) =
        *reinterpret_cast<unsigned*>(two);
  }
}

// =====================================================================
// Fully fused. Grid 256 = (b, o-stripe 64). 1024 threads (16 waves).
// Pass A (16 steps x 128 i, 1 barrier/step, no duplicated work):
//   wave (oh, iq): QK 32i x 16o (quad-interleave, in-register E) ->
//   PV over all 64 v. Epilogue: U reduce over iq, L2-norm -> values,
//   invD. Pass B: barrier-free, LDS-free weights (direct-global K/Q).
// =====================================================================
__global__ void __launch_bounds__(1024, 4) attn_fused(
    const float* __restrict__ key, const float* __restrict__ query,
    const float* __restrict__ value, float* __restrict__ out)
{
  __shared__ __align__(16) char smem[65536];
  __shared__ float Red[16][16];
  __shared__ float InvD[OS];
  __shared__ float Nn[OS];
  unsigned short* Kt0 = reinterpret_cast<unsigned short*>(smem);
  unsigned short* Kt1 = reinterpret_cast<unsigned short*>(smem + 16384);
  unsigned short* Vt0 = reinterpret_cast<unsigned short*>(smem + 32768);
  unsigned short* Vt1 = reinterpret_cast<unsigned short*>(smem + 49152);
  float* Ured = reinterpret_cast<float*>(smem);            // 64*68*4 = 17408B
  float* R2   = reinterpret_cast<float*>(smem + 20480);    // 16*64*4 = 4096B

  const int tid  = threadIdx.x;
  const int lane = tid & 63;
  const int w    = tid >> 6;      // wave 0..15
  const int l15  = lane & 15;
  const int l4   = lane >> 4;
  const int oh   = w >> 2;        // 16-o group (pass A)
  const int iq   = w & 3;         // 32-i quarter of each 128-i step

  const int b  = blockIdx.x & 7;          // batch -> XCD
  const int o0 = (blockIdx.x >> 3) * OS;  // o-stripe base

  const float* Kg = key   + (size_t)b * NN * KK;
  const float* Qg = query + (size_t)b * NN * KK;
  const float* Vg = value + (size_t)b * NN * VV;
  float* outV = out + (size_t)b * VV * NN;
  float* outW = out + (size_t)NB * VV * NN + (size_t)b * NN * NN;

  // Q fragments (B-op in pass A): lane l15 = o, k = l4*8+j
  bfrag qb0, qb1;
  {
    const float* qr = Qg + (size_t)(o0 + oh * 16 + l15) * KK;
    qb0 = g_frag(qr + l4 * 8);
    qb1 = g_frag(qr + 32 + l4 * 8);
  }

  // staging coords: waves 0-7 stage K (8192 el), waves 8-15 stage V
  const int krow = tid >> 2;           // 0..127 (tid<512)
  const int kel  = (tid & 3) * 16;
  const int kcb  = (tid & 3) * 32;
  const int t2   = tid - 512;
  const int vil  = (t2 & 63) * 2;      // i-pair
  const int vg8  = (t2 >> 6) & 7;     // v group (8 v)
  const int vv0  = vg8 * 8;

  KS ks; VS vs;
  if (tid < 512) { k_load(ks, Kg + (size_t)krow * KK + kel); }
  else           { v_load(vs, Vg + (size_t)vil * VV + vv0); }
  if (tid < 512) k_write(ks, Kt0, krow, kcb);
  else           v_write(vs, Vt0, vil, vv0);
  __syncthreads();

  // quad-interleaved A-row permutation: slot p -> i = (p&3) + 8*(p>>2)
  const int ip = (l15 & 3) + ((l15 >> 2) * 8);

  f32x4 uacc[4];
#pragma unroll
  for (int vg = 0; vg < 4; ++vg) { f32x4 z = {0.f,0.f,0.f,0.f}; uacc[vg] = z; }
  float Dacc = 0.f;

  // ================= PASS A =================
  for (int t = 0; t < NTA; ++t) {
    unsigned short* Kc = (t & 1) ? Kt1 : Kt0;
    unsigned short* Vc = (t & 1) ? Vt1 : Vt0;
    unsigned short* Kn = (t & 1) ? Kt0 : Kt1;
    unsigned short* Vn = (t & 1) ? Vt0 : Vt1;
    if (t + 1 < NTA) {
      if (tid < 512) k_load(ks, Kg + (size_t)((t + 1) * ITEP + krow) * KK + kel);
      else           v_load(vs, Vg + (size_t)((t + 1) * ITEP + vil) * VV + vv0);
    }
    // QK: A = K rows (quad-interleaved within iq's 32 i), B = Q.
    // Lane ends with E at (i = iq*32 + l4*8 + 0..7, o = oh*16 + l15)
    // = exactly the PV B-fragment, in-register.
    const int r1 = iq * 32 + ip;
    bfrag ka10 = kfrag(Kc, r1,     l4 * 16);
    bfrag ka11 = kfrag(Kc, r1,     64 + l4 * 16);
    bfrag ka20 = kfrag(Kc, r1 + 4, l4 * 16);
    bfrag ka21 = kfrag(Kc, r1 + 4, 64 + l4 * 16);
    f32x4 z1 = {0.f,0.f,0.f,0.f}, z2 = {0.f,0.f,0.f,0.f};
    z1 = __builtin_amdgcn_mfma_f32_16x16x32_bf16(ka10, qb0, z1, 0, 0, 0);
    z1 = __builtin_amdgcn_mfma_f32_16x16x32_bf16(ka11, qb1, z1, 0, 0, 0);
    z2 = __builtin_amdgcn_mfma_f32_16x16x32_bf16(ka20, qb0, z2, 0, 0, 0);
    z2 = __builtin_amdgcn_mfma_f32_16x16x32_bf16(ka21, qb1, z2, 0, 0, 0);
    f32x4 e1, e2;
#pragma unroll
    for (int r = 0; r < 4; ++r) e1[r] = exp2f(z1[r] * SCALE);
#pragma unroll
    for (int r = 0; r < 4; ++r) e2[r] = exp2f(z2[r] * SCALE);
    Dacc += e1[0] + e1[1] + e1[2] + e1[3] + e2[0] + e2[1] + e2[2] + e2[3];
    bfrag eb;
#pragma unroll
    for (int r = 0; r < 4; ++r) eb[r]     = (__bf16)e1[r];
#pragma unroll
    for (int r = 0; r < 4; ++r) eb[4 + r] = (__bf16)e2[r];
    // PV: U[v][o] += V^T.E over this wave's 32 i, all 64 v
#pragma unroll
    for (int vg = 0; vg < 4; ++vg) {
      bfrag va = vfrag(Vc, vg * 16 + l15, iq * 64 + l4 * 16);
      uacc[vg] = __builtin_amdgcn_mfma_f32_16x16x32_bf16(va, eb, uacc[vg], 0, 0, 0);
    }
    if (t + 1 < NTA) {
      if (tid < 512) k_write(ks, Kn, krow, kcb);
      else           v_write(vs, Vn, vil, vv0);
    }
    __syncthreads();
  }

  // ---- D: reduce over l4 -> Red[w][o-within-group] ----
  {
    float d = Dacc;
    d += __shfl_xor(d, 16, 64);
    d += __shfl_xor(d, 32, 64);
    if (lane < 16) Red[w][lane] = d;
  }
  // ---- U: sequential reduce over the 4 iq copies (overlay on Kt/Vt) ----
#pragma unroll
  for (int q = 0; q < 4; ++q) {
    if (iq == q) {
#pragma unroll
      for (int vg = 0; vg < 4; ++vg)
#pragma unroll
        for (int r = 0; r < 4; ++r) {
          const int idx = (vg * 16 + l4 * 4 + r) * UST + oh * 16 + l15;
          if (q == 0) Ured[idx] = uacc[vg][r];
          else        Ured[idx] += uacc[vg][r];
        }
    }
    __syncthreads();
  }
  // ---- ssq partials (16 v-groups x 64 o) ----
  {
    const int vgr = tid >> 6;        // 0..15 (4 v each)
    const int o   = tid & 63;
    float s = 0.f;
#pragma unroll
    for (int j = 0; j < 4; ++j) {
      float x = Ured[(vgr * 4 + j) * UST + o];
      s += x * x;
    }
    R2[vgr * 64 + o] = s;
  }
  __syncthreads();
  if (tid < OS) {
    float n = 0.f;
#pragma unroll
    for (int g = 0; g < 16; ++g) n += R2[g * 64 + tid];
    Nn[tid] = 1.f / (sqrtf(n) + 1e-12f);
  } else if (tid < 2 * OS) {
    const int o = tid - OS;
    const int ohh = o >> 4;
    InvD[o] = 1.f / (Red[ohh * 4 + 0][o & 15] + Red[ohh * 4 + 1][o & 15] +
                     Red[ohh * 4 + 2][o & 15] + Red[ohh * 4 + 3][o & 15]);
  }
  __syncthreads();
  // ---- values: L2-normalized columns (softmax denom cancels) ----
  {
    const int v  = tid >> 4;
    const int og = (tid & 15) * 4;
    f32x4 u = *reinterpret_cast<f32x4*>(&Ured[v * UST + og]);
    f32x4 r;
#pragma unroll
    for (int j = 0; j < 4; ++j) r[j] = u[j] * Nn[og + j];
    *reinterpret_cast<f32x4*>(&outV[(size_t)v * NN + o0 + og]) = r;
  }

  // ================= PASS B: weights (no LDS, no barriers) =================
  const int ohf = w & 1;      // 32-o half
  const int ic  = w >> 1;     // 0..7, 256-i chunk
  bfrag qA[2][2];
  f32x4 id[2];
#pragma unroll
  for (int g = 0; g < 2; ++g) {
    const float* qr = Qg + (size_t)(o0 + ohf * 32 + g * 16 + l15) * KK;
    qA[g][0] = g_frag(qr + l4 * 8);
    qA[g][1] = g_frag(qr + 32 + l4 * 8);
    id[g] = *reinterpret_cast<const f32x4*>(&InvD[ohf * 32 + g * 16 + l4 * 4]);
  }
  for (int t = 0; t < 16; ++t) {
    const int ibase = ic * 256 + t * 16;
    const float* kr = Kg + (size_t)(ibase + l15) * KK;
    bfrag kb0 = g_frag(kr + l4 * 8);
    bfrag kb1 = g_frag(kr + 32 + l4 * 8);
#pragma unroll
    for (int g = 0; g < 2; ++g) {
      f32x4 z = {0.f,0.f,0.f,0.f};
      z = __builtin_amdgcn_mfma_f32_16x16x32_bf16(qA[g][0], kb0, z, 0, 0, 0);
      z = __builtin_amdgcn_mfma_f32_16x16x32_bf16(qA[g][1], kb1, z, 0, 0, 0);
      f32x4 ww;
#pragma unroll
      for (int r = 0; r < 4; ++r) ww[r] = exp2f(z[r] * SCALE) * id[g][r];
      // weights[i = ibase + l15][o = o0 + ohf*32 + g*16 + l4*4 .. +3]
      float* wp = outW + (size_t)(ibase + l15) * NN + o0 + ohf * 32 + g * 16 + l4 * 4;
      *reinterpret_cast<f32x4*>(wp) = ww;
    }
  }
}

extern "C" void kernel_launch(void* const* d_in, const int* in_sizes, int n_in,
                              void* d_out, int out_size, void* d_ws, size_t ws_size,
                              hipStream_t stream) {
  (void)in_sizes; (void)n_in; (void)d_ws; (void)ws_size; (void)out_size;
  const float* key   = (const float*)d_in[0];
  const float* query = (const float*)d_in[1];
  const float* value = (const float*)d_in[2];
  float* out = (float*)d_out;
  attn_fused<<<dim3(NB * (NN / OS)), dim3(1024), 0, stream>>>(key, query, value, out);
}